// Round 13
// baseline (111.048 us; speedup 1.0000x reference)
//
#include <hip/hip_runtime.h>
#include <hip/hip_bf16.h>
#include <float.h>

// Problem constants
constexpr int B   = 2;
constexpr int N   = 16384;
constexpr int S   = 4096;
constexpr int INC = 256;
constexpr int OUTC = 128;

// Workspace layout: down_f scratch (4 MB) + W2^T bf16 (32 KB).
constexpr size_t OFF_DOWNF = 0;
constexpr size_t OFF_W2T   = 4194304;

typedef short short4_t __attribute__((ext_vector_type(4)));
typedef short short8_t __attribute__((ext_vector_type(8)));
typedef float f32x4    __attribute__((ext_vector_type(4)));

__device__ __forceinline__ unsigned short f2bf(float f) {
    unsigned u = __builtin_bit_cast(unsigned, f);
    u += 0x7fffu + ((u >> 16) & 1u);          // round-to-nearest-even
    return (unsigned short)(u >> 16);
}

// ---------------------------------------------------------------------------
// k_prep: W2 (128x128 f32, row-major [k][col]) -> W2t (bf16, [col][k]).
// One-time, 16384 elements, 64 blocks.
// ---------------------------------------------------------------------------
__global__ __launch_bounds__(256) void k_prep(const float* __restrict__ W2,
                                              short* __restrict__ W2t) {
    const int t = blockIdx.x * 256 + threadIdx.x;   // 0..16383
    const int k = t >> 7, col = t & 127;
    W2t[col * 128 + k] = (short)f2bf(W2[t]);
}

// ---------------------------------------------------------------------------
// MFMA GEMM (unchanged, passing since R6) — used for down_f only.
// ---------------------------------------------------------------------------
template <int K, int ROWS>
__global__ __launch_bounds__(256) void k_mfma(const float* __restrict__ f,
                                              const float* __restrict__ W,
                                              const float* __restrict__ bias,
                                              float* __restrict__ outf) {
    constexpr int MF = ROWS / 16;
    constexpr int KS = K / 32;
    __shared__ __align__(16) short smem[K * 128];

    const int tid  = threadIdx.x;
    const int lane = tid & 63;
    const int wv   = tid >> 6;
    const int rowbase = blockIdx.x * ROWS;
    const int lo16 = lane & 15;
    const int hi8  = (lane >> 4) * 8;

    const float4* w4 = reinterpret_cast<const float4*>(W);
    for (int n = tid; n < K * 32; n += 256) {
        const float4 u = w4[n];
        short4_t s = { (short)f2bf(u.x), (short)f2bf(u.y),
                       (short)f2bf(u.z), (short)f2bf(u.w) };
        *reinterpret_cast<short4_t*>(&smem[n * 4]) = s;
    }
    __syncthreads();

    short8_t bf[KS][2];
    #pragma unroll
    for (int ks = 0; ks < KS; ++ks) {
        #pragma unroll
        for (int c = 0; c < 2; ++c) {
            const int col = wv * 32 + c * 16 + lo16;
            #pragma unroll
            for (int r = 0; r < 8; ++r)
                bf[ks][c][r] = smem[(ks * 32 + hi8 + r) * 128 + col];
        }
    }
    __syncthreads();

    const float4* a4 = reinterpret_cast<const float4*>(f + (size_t)rowbase * K);
    for (int n = tid; n < ROWS * K / 8; n += 256) {
        const int row   = n / (K / 8);
        const int k8    = (n % (K / 8)) * 8;
        const int base4 = (row * K + k8) >> 2;
        const float4 u = a4[base4];
        const float4 v = a4[base4 + 1];
        short8_t s = { (short)f2bf(u.x), (short)f2bf(u.y), (short)f2bf(u.z), (short)f2bf(u.w),
                       (short)f2bf(v.x), (short)f2bf(v.y), (short)f2bf(v.z), (short)f2bf(v.w) };
        const int idx = (row * K + k8) ^ ((row & 7) << 3);
        *reinterpret_cast<short8_t*>(&smem[idx]) = s;
    }
    __syncthreads();

    f32x4 acc[MF][2];
    #pragma unroll
    for (int m = 0; m < MF; ++m) {
        #pragma unroll
        for (int c = 0; c < 2; ++c) acc[m][c] = (f32x4){0.f, 0.f, 0.f, 0.f};
    }

    const int axor = (lane & 7) << 3;
    #pragma unroll
    for (int ks = 0; ks < KS; ++ks) {
        #pragma unroll
        for (int m = 0; m < MF; ++m) {
            const int aidx = ((m * 16 + lo16) * K + ks * 32 + hi8) ^ axor;
            const short8_t af = *reinterpret_cast<const short8_t*>(&smem[aidx]);
            acc[m][0] = __builtin_amdgcn_mfma_f32_16x16x32_bf16(af, bf[ks][0], acc[m][0], 0, 0, 0);
            acc[m][1] = __builtin_amdgcn_mfma_f32_16x16x32_bf16(af, bf[ks][1], acc[m][1], 0, 0, 0);
        }
    }

    #pragma unroll
    for (int c = 0; c < 2; ++c) {
        const int col = wv * 32 + c * 16 + lo16;
        const float bb = bias[col];
        #pragma unroll
        for (int m = 0; m < MF; ++m) {
            #pragma unroll
            for (int r = 0; r < 4; ++r) {
                const int row = rowbase + m * 16 + (lane >> 4) * 4 + r;
                outf[(size_t)row * 128 + col] = acc[m][c][r] + bb;
            }
        }
    }
}

// ---------------------------------------------------------------------------
// Insert macros (proven R3/R5/R7/R11/R12).
// ---------------------------------------------------------------------------
#define INS3M(d0, d1, d2, i0, i1, i2, dd, ss)                               \
    {                                                                       \
        const bool c0 = (dd) < d0, c1 = (dd) < d1, c2 = (dd) < d2;          \
        i2 = c1 ? i1 : (c2 ? (ss) : i2);                                    \
        i1 = c0 ? i0 : (c1 ? (ss) : i1);                                    \
        i0 = c0 ? (ss) : i0;                                                \
        d2 = fminf(fmaxf((dd), d1), d2);                                    \
        d1 = fminf(fmaxf((dd), d0), d1);                                    \
        d0 = fminf(d0, (dd));                                               \
    }

#define INS3L(d0, d1, d2, i0, i1, i2, dd, ss)                               \
    {                                                                       \
        const bool c0 = ((dd) < d0) | (((dd) == d0) & ((ss) < i0));         \
        const bool c1 = ((dd) < d1) | (((dd) == d1) & ((ss) < i1));         \
        const bool c2 = ((dd) < d2) | (((dd) == d2) & ((ss) < i2));         \
        i2 = c1 ? i1 : (c2 ? (ss) : i2);                                    \
        i1 = c0 ? i0 : (c1 ? (ss) : i1);                                    \
        i0 = c0 ? (ss) : i0;                                                \
        d2 = c1 ? d1 : (c2 ? (dd) : d2);                                    \
        d1 = c0 ? d0 : (c1 ? (dd) : d1);                                    \
        d0 = c0 ? (dd) : d0;                                                \
    }

// ---------------------------------------------------------------------------
// k_fused (R12 structure, W2 path hoisted):
//   Phase 1: stage A-tile (16 rows ofeat -> bf16, XOR-swizzled, LDS) and load
//     B-fragments DIRECTLY from L2-resident W2t via 8x 16B global loads.
//     -> no per-block W2 staging, no column LDS reads (the 1.18M conflicts).
//   Phase 2: wave-parallel 3-NN (R7/R11/R12-verbatim).
//   Phase 3: gather + epilogue (R12-verbatim).
// LDS: sA [0,4096) ; sx [4096,20736) ; si [20736,20928) ; sw [20928,21120).
// ---------------------------------------------------------------------------
__global__ __launch_bounds__(256) void k_fused(const float4* __restrict__ dxyzp,
                                               const float4* __restrict__ oxyzp,
                                               const float*  __restrict__ ofeat,
                                               const short*  __restrict__ W2t,
                                               const float*  __restrict__ b2,
                                               const float*  __restrict__ downf,
                                               float*        __restrict__ out) {
    __shared__ __align__(16) char lds[21120];
    short*  sA = reinterpret_cast<short*>(lds);             // [16*128] bf16
    float4* sx = reinterpret_cast<float4*>(lds + 4096);     // [16*65]
    int*    si = reinterpret_cast<int*>(lds + 20736);       // [48]
    float*  sw = reinterpret_cast<float*>(lds + 20928);     // [48]

    const int tid  = threadIdx.x;
    const int lane = tid & 63;
    const int wv   = tid >> 6;
    const int b     = blockIdx.x >> 10;           // 1024 blocks per batch
    const int qbase = (blockIdx.x & 1023) * 16;
    const int lo16 = lane & 15;
    const int hi8  = (lane >> 4) * 8;

    // ---- Phase 1a: stage A-tile (16 rows of ofeat, bf16, XOR-swizzled) ----
    {
        const float4* a4 = reinterpret_cast<const float4*>(
            ofeat + (size_t)(b * N + qbase) * 128);
        const int n    = tid;                     // 256 jobs, 1 per thread
        const int row  = n >> 4;                  // 0..15
        const int k8   = (n & 15) * 8;
        const int base4 = (row * 128 + k8) >> 2;
        const float4 u = a4[base4];
        const float4 v = a4[base4 + 1];
        short8_t s = { (short)f2bf(u.x), (short)f2bf(u.y), (short)f2bf(u.z), (short)f2bf(u.w),
                       (short)f2bf(v.x), (short)f2bf(v.y), (short)f2bf(v.z), (short)f2bf(v.w) };
        const int idx = (row * 128 + k8) ^ ((row & 7) << 3);
        *reinterpret_cast<short8_t*>(&sA[idx]) = s;
    }

    // ---- Phase 1b: B fragments straight from global W2t (L2-resident) ----
    short8_t bfr[4][2];
    #pragma unroll
    for (int c = 0; c < 2; ++c) {
        const int col = wv * 32 + c * 16 + lo16;
        const short* wt = W2t + col * 128;
        #pragma unroll
        for (int ks = 0; ks < 4; ++ks)
            bfr[ks][c] = *reinterpret_cast<const short8_t*>(wt + ks * 32 + hi8);
    }
    __syncthreads();

    // ---- MFMA: acc = ofeat_tile @ W2 (MF=1, KS=4) ----
    f32x4 acc[2] = { (f32x4){0.f,0.f,0.f,0.f}, (f32x4){0.f,0.f,0.f,0.f} };
    const int axor = (lane & 7) << 3;
    #pragma unroll
    for (int ks = 0; ks < 4; ++ks) {
        const int aidx = (lo16 * 128 + ks * 32 + hi8) ^ axor;
        const short8_t af = *reinterpret_cast<const short8_t*>(&sA[aidx]);
        acc[0] = __builtin_amdgcn_mfma_f32_16x16x32_bf16(af, bfr[ks][0], acc[0], 0, 0, 0);
        acc[1] = __builtin_amdgcn_mfma_f32_16x16x32_bf16(af, bfr[ks][1], acc[1], 0, 0, 0);
    }
    __syncthreads();

    // ---- Phase 2: 3-NN search (R7/R11/R12-verbatim) ----
    const int sp   = lane & 15;
    const int qs   = lane >> 4;
    const int slot = wv * 4 + qs;                 // 0..15 within block

    const float4 o = oxyzp[(size_t)b * N + qbase + slot];
    const float sumo = __fadd_rn(__fadd_rn(__fmul_rn(o.x, o.x), __fmul_rn(o.y, o.y)),
                                 __fmul_rn(o.z, o.z));

    float a0 = FLT_MAX, a1 = FLT_MAX, a2 = FLT_MAX;
    int   ai0 = 0, ai1 = 0, ai2 = 0;

    const float4* dpb = dxyzp + (size_t)b * S;

    for (int c = 0; c < 4; ++c) {
        if (c > 0) __syncthreads();
        const float4* dpc = dpb + c * 1024;
        for (int j = tid; j < 1024; j += 256) {
            float4 v = dpc[j];
            const float ss = __fadd_rn(__fadd_rn(__fmul_rn(v.x, v.x), __fmul_rn(v.y, v.y)),
                                       __fmul_rn(v.z, v.z));
            float4 w;
            w.x = v.x + v.x;
            w.y = v.y + v.y;
            w.z = v.z + v.z;
            w.w = ss;
            sx[(j >> 6) * 65 + (j & 63)] = w;
        }
        __syncthreads();

        const float4* base = &sx[sp * 65];
        const int g0 = c * 1024 + sp * 64;

        #pragma unroll 4
        for (int i = 0; i < 64; ++i) {
            const float4 q = base[i];
            const float dot2 = __fadd_rn(__fadd_rn(__fmul_rn(q.x, o.x), __fmul_rn(q.y, o.y)),
                                         __fmul_rn(q.z, o.z));
            const float dd = __fsub_rn(__fadd_rn(sumo, q.w), dot2);
            INS3M(a0, a1, a2, ai0, ai1, ai2, dd, g0 + i);
        }
    }

    #pragma unroll
    for (int m = 1; m <= 8; m <<= 1) {
        const float nd0 = __shfl_xor(a0, m, 64);
        const float nd1 = __shfl_xor(a1, m, 64);
        const float nd2 = __shfl_xor(a2, m, 64);
        const int   ni0 = __shfl_xor(ai0, m, 64);
        const int   ni1 = __shfl_xor(ai1, m, 64);
        const int   ni2 = __shfl_xor(ai2, m, 64);
        INS3L(a0, a1, a2, ai0, ai1, ai2, nd0, ni0);
        INS3L(a0, a1, a2, ai0, ai1, ai2, nd1, ni1);
        INS3L(a0, a1, a2, ai0, ai1, ai2, nd2, ni2);
    }

    if (sp == 0) {
        const float r0 = 1.0f / (a0 + 1e-8f);
        const float r1 = 1.0f / (a1 + 1e-8f);
        const float r2 = 1.0f / (a2 + 1e-8f);
        const float rs = __fadd_rn(__fadd_rn(r0, r1), r2);
        si[slot * 3 + 0] = ai0;
        si[slot * 3 + 1] = ai1;
        si[slot * 3 + 2] = ai2;
        sw[slot * 3 + 0] = r0 / rs;
        sw[slot * 3 + 1] = r1 / rs;
        sw[slot * 3 + 2] = r2 / rs;
    }
    __syncthreads();

    // ---- Phase 3: gather + epilogue, per acc element (R12-verbatim) ----
    const float* df = downf + (size_t)b * S * OUTC;
    float* ob = out + (size_t)(b * N + qbase) * OUTC;

    #pragma unroll
    for (int c = 0; c < 2; ++c) {
        const int col = wv * 32 + c * 16 + lo16;
        const float bb = b2[col];
        #pragma unroll
        for (int r = 0; r < 4; ++r) {
            const int row16 = (lane >> 4) * 4 + r;
            const int   j0 = si[row16 * 3 + 0];
            const int   j1 = si[row16 * 3 + 1];
            const int   j2 = si[row16 * 3 + 2];
            const float w0 = sw[row16 * 3 + 0];
            const float w1 = sw[row16 * 3 + 1];
            const float w2 = sw[row16 * 3 + 2];
            const float g = __fadd_rn(
                __fadd_rn(__fmul_rn(w0, df[(size_t)j0 * OUTC + col]),
                          __fmul_rn(w1, df[(size_t)j1 * OUTC + col])),
                __fmul_rn(w2, df[(size_t)j2 * OUTC + col]));
            ob[(size_t)row16 * OUTC + col] = (acc[c][r] + bb) + g;
        }
    }
}

// ---------------------------------------------------------------------------

extern "C" void kernel_launch(void* const* d_in, const int* in_sizes, int n_in,
                              void* d_out, int out_size, void* d_ws, size_t ws_size,
                              hipStream_t stream) {
    const float* dxyzp = (const float*)d_in[0];   // (B,S,4)
    const float* dfeat = (const float*)d_in[1];   // (B,S,256)
    const float* oxyzp = (const float*)d_in[2];   // (B,N,4)
    const float* ofeat = (const float*)d_in[3];   // (B,N,128)
    const float* W1    = (const float*)d_in[4];   // (256,128)
    const float* b1    = (const float*)d_in[5];   // (128)
    const float* W2    = (const float*)d_in[6];   // (128,128)
    const float* b2    = (const float*)d_in[7];   // (128)

    float* out   = (float*)d_out;                 // (B,N,128)
    char*  ws    = (char*)d_ws;
    float* downf = (float*)(ws + OFF_DOWNF);      // (B,S,128)
    short* W2t   = (short*)(ws + OFF_W2T);        // (128,128) bf16, transposed

    // W2^T bf16 (one-time, tiny)
    k_prep<<<64, 256, 0, stream>>>(W2, W2t);

    // down_f = down_features @ W1 + b1 -> workspace (MFMA bf16, frozen)
    k_mfma<INC, 32><<<(B * S) / 32, 256, 0, stream>>>(dfeat, W1, b1, downf);

    // Fused: ori_f GEMM + 3-NN search + interpolation -> out
    k_fused<<<B * (N / 16), 256, 0, stream>>>(
        (const float4*)dxyzp, (const float4*)oxyzp, ofeat, W2t, b2, downf, out);
}

// Round 14
// 98.801 us; speedup vs baseline: 1.1240x; 1.1240x over previous
//
#include <hip/hip_runtime.h>
#include <hip/hip_bf16.h>
#include <float.h>

// Problem constants
constexpr int B   = 2;
constexpr int N   = 16384;
constexpr int S   = 4096;
constexpr int INC = 256;
constexpr int OUTC = 128;

// Workspace layout: down_f scratch (4 MB) + W2^T bf16 (32 KB).
constexpr size_t OFF_DOWNF = 0;
constexpr size_t OFF_W2T   = 4194304;

typedef short short4_t __attribute__((ext_vector_type(4)));
typedef short short8_t __attribute__((ext_vector_type(8)));
typedef float f32x4    __attribute__((ext_vector_type(4)));

__device__ __forceinline__ unsigned short f2bf(float f) {
    unsigned u = __builtin_bit_cast(unsigned, f);
    u += 0x7fffu + ((u >> 16) & 1u);          // round-to-nearest-even
    return (unsigned short)(u >> 16);
}

// ---------------------------------------------------------------------------
// k_prep: W2 (128x128 f32, row-major [k][col]) -> W2t (bf16, [col][k]).
// ---------------------------------------------------------------------------
__global__ __launch_bounds__(256) void k_prep(const float* __restrict__ W2,
                                              short* __restrict__ W2t) {
    const int t = blockIdx.x * 256 + threadIdx.x;   // 0..16383
    const int k = t >> 7, col = t & 127;
    W2t[col * 128 + k] = (short)f2bf(W2[t]);
}

// ---------------------------------------------------------------------------
// MFMA GEMM (unchanged, passing since R6) — used for down_f only.
// ---------------------------------------------------------------------------
template <int K, int ROWS>
__global__ __launch_bounds__(256) void k_mfma(const float* __restrict__ f,
                                              const float* __restrict__ W,
                                              const float* __restrict__ bias,
                                              float* __restrict__ outf) {
    constexpr int MF = ROWS / 16;
    constexpr int KS = K / 32;
    __shared__ __align__(16) short smem[K * 128];

    const int tid  = threadIdx.x;
    const int lane = tid & 63;
    const int wv   = tid >> 6;
    const int rowbase = blockIdx.x * ROWS;
    const int lo16 = lane & 15;
    const int hi8  = (lane >> 4) * 8;

    const float4* w4 = reinterpret_cast<const float4*>(W);
    for (int n = tid; n < K * 32; n += 256) {
        const float4 u = w4[n];
        short4_t s = { (short)f2bf(u.x), (short)f2bf(u.y),
                       (short)f2bf(u.z), (short)f2bf(u.w) };
        *reinterpret_cast<short4_t*>(&smem[n * 4]) = s;
    }
    __syncthreads();

    short8_t bf[KS][2];
    #pragma unroll
    for (int ks = 0; ks < KS; ++ks) {
        #pragma unroll
        for (int c = 0; c < 2; ++c) {
            const int col = wv * 32 + c * 16 + lo16;
            #pragma unroll
            for (int r = 0; r < 8; ++r)
                bf[ks][c][r] = smem[(ks * 32 + hi8 + r) * 128 + col];
        }
    }
    __syncthreads();

    const float4* a4 = reinterpret_cast<const float4*>(f + (size_t)rowbase * K);
    for (int n = tid; n < ROWS * K / 8; n += 256) {
        const int row   = n / (K / 8);
        const int k8    = (n % (K / 8)) * 8;
        const int base4 = (row * K + k8) >> 2;
        const float4 u = a4[base4];
        const float4 v = a4[base4 + 1];
        short8_t s = { (short)f2bf(u.x), (short)f2bf(u.y), (short)f2bf(u.z), (short)f2bf(u.w),
                       (short)f2bf(v.x), (short)f2bf(v.y), (short)f2bf(v.z), (short)f2bf(v.w) };
        const int idx = (row * K + k8) ^ ((row & 7) << 3);
        *reinterpret_cast<short8_t*>(&smem[idx]) = s;
    }
    __syncthreads();

    f32x4 acc[MF][2];
    #pragma unroll
    for (int m = 0; m < MF; ++m) {
        #pragma unroll
        for (int c = 0; c < 2; ++c) acc[m][c] = (f32x4){0.f, 0.f, 0.f, 0.f};
    }

    const int axor = (lane & 7) << 3;
    #pragma unroll
    for (int ks = 0; ks < KS; ++ks) {
        #pragma unroll
        for (int m = 0; m < MF; ++m) {
            const int aidx = ((m * 16 + lo16) * K + ks * 32 + hi8) ^ axor;
            const short8_t af = *reinterpret_cast<const short8_t*>(&smem[aidx]);
            acc[m][0] = __builtin_amdgcn_mfma_f32_16x16x32_bf16(af, bf[ks][0], acc[m][0], 0, 0, 0);
            acc[m][1] = __builtin_amdgcn_mfma_f32_16x16x32_bf16(af, bf[ks][1], acc[m][1], 0, 0, 0);
        }
    }

    #pragma unroll
    for (int c = 0; c < 2; ++c) {
        const int col = wv * 32 + c * 16 + lo16;
        const float bb = bias[col];
        #pragma unroll
        for (int m = 0; m < MF; ++m) {
            #pragma unroll
            for (int r = 0; r < 4; ++r) {
                const int row = rowbase + m * 16 + (lane >> 4) * 4 + r;
                outf[(size_t)row * 128 + col] = acc[m][c][r] + bb;
            }
        }
    }
}

// ---------------------------------------------------------------------------
// Insert macros. INS3M hot-loop value updates now use v_med3_f32 directly:
// given sorted invariant d0<=d1<=d2,
//   new d2 = med3(d1, d2, dd)  (dd<d1 -> d1 ; d1<=dd<d2 -> dd ; else d2)
//   new d1 = med3(d0, d1, dd)  (computed with OLD d0)
//   new d0 = min(d0, dd)
// Bit-identical decisions to the R13 fminf/fmaxf form; 2 fewer VALU/pair.
// ---------------------------------------------------------------------------
#define INS3M(d0, d1, d2, i0, i1, i2, dd, ss)                               \
    {                                                                       \
        const bool c0 = (dd) < d0, c1 = (dd) < d1, c2 = (dd) < d2;          \
        i2 = c1 ? i1 : (c2 ? (ss) : i2);                                    \
        i1 = c0 ? i0 : (c1 ? (ss) : i1);                                    \
        i0 = c0 ? (ss) : i0;                                                \
        d2 = __builtin_amdgcn_fmed3f(d1, d2, (dd));                         \
        d1 = __builtin_amdgcn_fmed3f(d0, d1, (dd));                         \
        d0 = fminf(d0, (dd));                                               \
    }

#define INS3L(d0, d1, d2, i0, i1, i2, dd, ss)                               \
    {                                                                       \
        const bool c0 = ((dd) < d0) | (((dd) == d0) & ((ss) < i0));         \
        const bool c1 = ((dd) < d1) | (((dd) == d1) & ((ss) < i1));         \
        const bool c2 = ((dd) < d2) | (((dd) == d2) & ((ss) < i2));         \
        i2 = c1 ? i1 : (c2 ? (ss) : i2);                                    \
        i1 = c0 ? i0 : (c1 ? (ss) : i1);                                    \
        i0 = c0 ? (ss) : i0;                                                \
        d2 = c1 ? d1 : (c2 ? (dd) : d2);                                    \
        d1 = c0 ? d0 : (c1 ? (dd) : d1);                                    \
        d0 = c0 ? (dd) : d0;                                                \
    }

// ---------------------------------------------------------------------------
// k_fused (R13 structure; hot loop: med3 insert + full unroll).
// ---------------------------------------------------------------------------
__global__ __launch_bounds__(256) void k_fused(const float4* __restrict__ dxyzp,
                                               const float4* __restrict__ oxyzp,
                                               const float*  __restrict__ ofeat,
                                               const short*  __restrict__ W2t,
                                               const float*  __restrict__ b2,
                                               const float*  __restrict__ downf,
                                               float*        __restrict__ out) {
    __shared__ __align__(16) char lds[21120];
    short*  sA = reinterpret_cast<short*>(lds);             // [16*128] bf16
    float4* sx = reinterpret_cast<float4*>(lds + 4096);     // [16*65]
    int*    si = reinterpret_cast<int*>(lds + 20736);       // [48]
    float*  sw = reinterpret_cast<float*>(lds + 20928);     // [48]

    const int tid  = threadIdx.x;
    const int lane = tid & 63;
    const int wv   = tid >> 6;
    const int b     = blockIdx.x >> 10;           // 1024 blocks per batch
    const int qbase = (blockIdx.x & 1023) * 16;
    const int lo16 = lane & 15;
    const int hi8  = (lane >> 4) * 8;

    // ---- Phase 1a: stage A-tile (16 rows of ofeat, bf16, XOR-swizzled) ----
    {
        const float4* a4 = reinterpret_cast<const float4*>(
            ofeat + (size_t)(b * N + qbase) * 128);
        const int n    = tid;                     // 256 jobs, 1 per thread
        const int row  = n >> 4;                  // 0..15
        const int k8   = (n & 15) * 8;
        const int base4 = (row * 128 + k8) >> 2;
        const float4 u = a4[base4];
        const float4 v = a4[base4 + 1];
        short8_t s = { (short)f2bf(u.x), (short)f2bf(u.y), (short)f2bf(u.z), (short)f2bf(u.w),
                       (short)f2bf(v.x), (short)f2bf(v.y), (short)f2bf(v.z), (short)f2bf(v.w) };
        const int idx = (row * 128 + k8) ^ ((row & 7) << 3);
        *reinterpret_cast<short8_t*>(&sA[idx]) = s;
    }

    // ---- Phase 1b: B fragments straight from global W2t (L2-resident) ----
    short8_t bfr[4][2];
    #pragma unroll
    for (int c = 0; c < 2; ++c) {
        const int col = wv * 32 + c * 16 + lo16;
        const short* wt = W2t + col * 128;
        #pragma unroll
        for (int ks = 0; ks < 4; ++ks)
            bfr[ks][c] = *reinterpret_cast<const short8_t*>(wt + ks * 32 + hi8);
    }
    __syncthreads();

    // ---- MFMA: acc = ofeat_tile @ W2 (MF=1, KS=4) ----
    f32x4 acc[2] = { (f32x4){0.f,0.f,0.f,0.f}, (f32x4){0.f,0.f,0.f,0.f} };
    const int axor = (lane & 7) << 3;
    #pragma unroll
    for (int ks = 0; ks < 4; ++ks) {
        const int aidx = (lo16 * 128 + ks * 32 + hi8) ^ axor;
        const short8_t af = *reinterpret_cast<const short8_t*>(&sA[aidx]);
        acc[0] = __builtin_amdgcn_mfma_f32_16x16x32_bf16(af, bfr[ks][0], acc[0], 0, 0, 0);
        acc[1] = __builtin_amdgcn_mfma_f32_16x16x32_bf16(af, bfr[ks][1], acc[1], 0, 0, 0);
    }
    __syncthreads();

    // ---- Phase 2: 3-NN search (R7/R11/R12/R13 structure) ----
    const int sp   = lane & 15;
    const int qs   = lane >> 4;
    const int slot = wv * 4 + qs;                 // 0..15 within block

    const float4 o = oxyzp[(size_t)b * N + qbase + slot];
    const float sumo = __fadd_rn(__fadd_rn(__fmul_rn(o.x, o.x), __fmul_rn(o.y, o.y)),
                                 __fmul_rn(o.z, o.z));

    float a0 = FLT_MAX, a1 = FLT_MAX, a2 = FLT_MAX;
    int   ai0 = 0, ai1 = 0, ai2 = 0;

    const float4* dpb = dxyzp + (size_t)b * S;

    for (int c = 0; c < 4; ++c) {
        if (c > 0) __syncthreads();
        const float4* dpc = dpb + c * 1024;
        for (int j = tid; j < 1024; j += 256) {
            float4 v = dpc[j];
            const float ss = __fadd_rn(__fadd_rn(__fmul_rn(v.x, v.x), __fmul_rn(v.y, v.y)),
                                       __fmul_rn(v.z, v.z));
            float4 w;
            w.x = v.x + v.x;
            w.y = v.y + v.y;
            w.z = v.z + v.z;
            w.w = ss;
            sx[(j >> 6) * 65 + (j & 63)] = w;
        }
        __syncthreads();

        const float4* base = &sx[sp * 65];
        const int g0 = c * 1024 + sp * 64;

        #pragma unroll
        for (int i = 0; i < 64; ++i) {
            const float4 q = base[i];
            const float dot2 = __fadd_rn(__fadd_rn(__fmul_rn(q.x, o.x), __fmul_rn(q.y, o.y)),
                                         __fmul_rn(q.z, o.z));
            const float dd = __fsub_rn(__fadd_rn(sumo, q.w), dot2);
            INS3M(a0, a1, a2, ai0, ai1, ai2, dd, g0 + i);
        }
    }

    #pragma unroll
    for (int m = 1; m <= 8; m <<= 1) {
        const float nd0 = __shfl_xor(a0, m, 64);
        const float nd1 = __shfl_xor(a1, m, 64);
        const float nd2 = __shfl_xor(a2, m, 64);
        const int   ni0 = __shfl_xor(ai0, m, 64);
        const int   ni1 = __shfl_xor(ai1, m, 64);
        const int   ni2 = __shfl_xor(ai2, m, 64);
        INS3L(a0, a1, a2, ai0, ai1, ai2, nd0, ni0);
        INS3L(a0, a1, a2, ai0, ai1, ai2, nd1, ni1);
        INS3L(a0, a1, a2, ai0, ai1, ai2, nd2, ni2);
    }

    if (sp == 0) {
        const float r0 = 1.0f / (a0 + 1e-8f);
        const float r1 = 1.0f / (a1 + 1e-8f);
        const float r2 = 1.0f / (a2 + 1e-8f);
        const float rs = __fadd_rn(__fadd_rn(r0, r1), r2);
        si[slot * 3 + 0] = ai0;
        si[slot * 3 + 1] = ai1;
        si[slot * 3 + 2] = ai2;
        sw[slot * 3 + 0] = r0 / rs;
        sw[slot * 3 + 1] = r1 / rs;
        sw[slot * 3 + 2] = r2 / rs;
    }
    __syncthreads();

    // ---- Phase 3: gather + epilogue, per acc element (R12/R13-verbatim) ----
    const float* df = downf + (size_t)b * S * OUTC;
    float* ob = out + (size_t)(b * N + qbase) * OUTC;

    #pragma unroll
    for (int c = 0; c < 2; ++c) {
        const int col = wv * 32 + c * 16 + lo16;
        const float bb = b2[col];
        #pragma unroll
        for (int r = 0; r < 4; ++r) {
            const int row16 = (lane >> 4) * 4 + r;
            const int   j0 = si[row16 * 3 + 0];
            const int   j1 = si[row16 * 3 + 1];
            const int   j2 = si[row16 * 3 + 2];
            const float w0 = sw[row16 * 3 + 0];
            const float w1 = sw[row16 * 3 + 1];
            const float w2 = sw[row16 * 3 + 2];
            const float g = __fadd_rn(
                __fadd_rn(__fmul_rn(w0, df[(size_t)j0 * OUTC + col]),
                          __fmul_rn(w1, df[(size_t)j1 * OUTC + col])),
                __fmul_rn(w2, df[(size_t)j2 * OUTC + col]));
            ob[(size_t)row16 * OUTC + col] = (acc[c][r] + bb) + g;
        }
    }
}

// ---------------------------------------------------------------------------

extern "C" void kernel_launch(void* const* d_in, const int* in_sizes, int n_in,
                              void* d_out, int out_size, void* d_ws, size_t ws_size,
                              hipStream_t stream) {
    const float* dxyzp = (const float*)d_in[0];   // (B,S,4)
    const float* dfeat = (const float*)d_in[1];   // (B,S,256)
    const float* oxyzp = (const float*)d_in[2];   // (B,N,4)
    const float* ofeat = (const float*)d_in[3];   // (B,N,128)
    const float* W1    = (const float*)d_in[4];   // (256,128)
    const float* b1    = (const float*)d_in[5];   // (128)
    const float* W2    = (const float*)d_in[6];   // (128,128)
    const float* b2    = (const float*)d_in[7];   // (128)

    float* out   = (float*)d_out;                 // (B,N,128)
    char*  ws    = (char*)d_ws;
    float* downf = (float*)(ws + OFF_DOWNF);      // (B,S,128)
    short* W2t   = (short*)(ws + OFF_W2T);        // (128,128) bf16, transposed

    // W2^T bf16 (one-time, tiny)
    k_prep<<<64, 256, 0, stream>>>(W2, W2t);

    // down_f = down_features @ W1 + b1 -> workspace (MFMA bf16, frozen)
    k_mfma<INC, 32><<<(B * S) / 32, 256, 0, stream>>>(dfeat, W1, b1, downf);

    // Fused: ori_f GEMM + 3-NN search + interpolation -> out
    k_fused<<<B * (N / 16), 256, 0, stream>>>(
        (const float4*)dxyzp, (const float4*)oxyzp, ofeat, W2t, b2, downf, out);
}

// Round 16
// 98.741 us; speedup vs baseline: 1.1246x; 1.0006x over previous
//
#include <hip/hip_runtime.h>
#include <hip/hip_bf16.h>
#include <float.h>

// Problem constants
constexpr int B   = 2;
constexpr int N   = 16384;
constexpr int S   = 4096;
constexpr int INC = 256;
constexpr int OUTC = 128;

// Workspace layout: down_f scratch (4 MB) + W2^T bf16 (32 KB).
constexpr size_t OFF_DOWNF = 0;
constexpr size_t OFF_W2T   = 4194304;

typedef short short4_t __attribute__((ext_vector_type(4)));
typedef short short8_t __attribute__((ext_vector_type(8)));
typedef float f32x4    __attribute__((ext_vector_type(4)));

__device__ __forceinline__ unsigned short f2bf(float f) {
    unsigned u = __builtin_bit_cast(unsigned, f);
    u += 0x7fffu + ((u >> 16) & 1u);          // round-to-nearest-even
    return (unsigned short)(u >> 16);
}

// ---------------------------------------------------------------------------
// k_prep: W2 (128x128 f32, row-major [k][col]) -> W2t (bf16, [col][k]).
// ---------------------------------------------------------------------------
__global__ __launch_bounds__(256) void k_prep(const float* __restrict__ W2,
                                              short* __restrict__ W2t) {
    const int t = blockIdx.x * 256 + threadIdx.x;   // 0..16383
    const int k = t >> 7, col = t & 127;
    W2t[col * 128 + k] = (short)f2bf(W2[t]);
}

// ---------------------------------------------------------------------------
// MFMA GEMM (unchanged, passing since R6) — used for down_f only.
// ---------------------------------------------------------------------------
template <int K, int ROWS>
__global__ __launch_bounds__(256) void k_mfma(const float* __restrict__ f,
                                              const float* __restrict__ W,
                                              const float* __restrict__ bias,
                                              float* __restrict__ outf) {
    constexpr int MF = ROWS / 16;
    constexpr int KS = K / 32;
    __shared__ __align__(16) short smem[K * 128];

    const int tid  = threadIdx.x;
    const int lane = tid & 63;
    const int wv   = tid >> 6;
    const int rowbase = blockIdx.x * ROWS;
    const int lo16 = lane & 15;
    const int hi8  = (lane >> 4) * 8;

    const float4* w4 = reinterpret_cast<const float4*>(W);
    for (int n = tid; n < K * 32; n += 256) {
        const float4 u = w4[n];
        short4_t s = { (short)f2bf(u.x), (short)f2bf(u.y),
                       (short)f2bf(u.z), (short)f2bf(u.w) };
        *reinterpret_cast<short4_t*>(&smem[n * 4]) = s;
    }
    __syncthreads();

    short8_t bf[KS][2];
    #pragma unroll
    for (int ks = 0; ks < KS; ++ks) {
        #pragma unroll
        for (int c = 0; c < 2; ++c) {
            const int col = wv * 32 + c * 16 + lo16;
            #pragma unroll
            for (int r = 0; r < 8; ++r)
                bf[ks][c][r] = smem[(ks * 32 + hi8 + r) * 128 + col];
        }
    }
    __syncthreads();

    const float4* a4 = reinterpret_cast<const float4*>(f + (size_t)rowbase * K);
    for (int n = tid; n < ROWS * K / 8; n += 256) {
        const int row   = n / (K / 8);
        const int k8    = (n % (K / 8)) * 8;
        const int base4 = (row * K + k8) >> 2;
        const float4 u = a4[base4];
        const float4 v = a4[base4 + 1];
        short8_t s = { (short)f2bf(u.x), (short)f2bf(u.y), (short)f2bf(u.z), (short)f2bf(u.w),
                       (short)f2bf(v.x), (short)f2bf(v.y), (short)f2bf(v.z), (short)f2bf(v.w) };
        const int idx = (row * K + k8) ^ ((row & 7) << 3);
        *reinterpret_cast<short8_t*>(&smem[idx]) = s;
    }
    __syncthreads();

    f32x4 acc[MF][2];
    #pragma unroll
    for (int m = 0; m < MF; ++m) {
        #pragma unroll
        for (int c = 0; c < 2; ++c) acc[m][c] = (f32x4){0.f, 0.f, 0.f, 0.f};
    }

    const int axor = (lane & 7) << 3;
    #pragma unroll
    for (int ks = 0; ks < KS; ++ks) {
        #pragma unroll
        for (int m = 0; m < MF; ++m) {
            const int aidx = ((m * 16 + lo16) * K + ks * 32 + hi8) ^ axor;
            const short8_t af = *reinterpret_cast<const short8_t*>(&smem[aidx]);
            acc[m][0] = __builtin_amdgcn_mfma_f32_16x16x32_bf16(af, bf[ks][0], acc[m][0], 0, 0, 0);
            acc[m][1] = __builtin_amdgcn_mfma_f32_16x16x32_bf16(af, bf[ks][1], acc[m][1], 0, 0, 0);
        }
    }

    #pragma unroll
    for (int c = 0; c < 2; ++c) {
        const int col = wv * 32 + c * 16 + lo16;
        const float bb = bias[col];
        #pragma unroll
        for (int m = 0; m < MF; ++m) {
            #pragma unroll
            for (int r = 0; r < 4; ++r) {
                const int row = rowbase + m * 16 + (lane >> 4) * 4 + r;
                outf[(size_t)row * 128 + col] = acc[m][c][r] + bb;
            }
        }
    }
}

// ---------------------------------------------------------------------------
// Insert macros. INS3M hot-loop value updates use v_med3_f32 directly:
// given sorted invariant d0<=d1<=d2,
//   new d2 = med3(d1, d2, dd) ; new d1 = med3(d0, d1, dd) (OLD d0) ;
//   new d0 = min(d0, dd). Bit-identical decisions to the min/max form.
// SESSION LAW: these insert chains must stay in straight-line or
// fully-unrolled uniform code. Every build placing them under
// data-dependent control flow (serial runtime loops R8-R10, __any-guard
// R15) failed with absmax 0.98 despite provably-correct logic.
// ---------------------------------------------------------------------------
#define INS3M(d0, d1, d2, i0, i1, i2, dd, ss)                               \
    {                                                                       \
        const bool c0 = (dd) < d0, c1 = (dd) < d1, c2 = (dd) < d2;          \
        i2 = c1 ? i1 : (c2 ? (ss) : i2);                                    \
        i1 = c0 ? i0 : (c1 ? (ss) : i1);                                    \
        i0 = c0 ? (ss) : i0;                                                \
        d2 = __builtin_amdgcn_fmed3f(d1, d2, (dd));                         \
        d1 = __builtin_amdgcn_fmed3f(d0, d1, (dd));                         \
        d0 = fminf(d0, (dd));                                               \
    }

#define INS3L(d0, d1, d2, i0, i1, i2, dd, ss)                               \
    {                                                                       \
        const bool c0 = ((dd) < d0) | (((dd) == d0) & ((ss) < i0));         \
        const bool c1 = ((dd) < d1) | (((dd) == d1) & ((ss) < i1));         \
        const bool c2 = ((dd) < d2) | (((dd) == d2) & ((ss) < i2));         \
        i2 = c1 ? i1 : (c2 ? (ss) : i2);                                    \
        i1 = c0 ? i0 : (c1 ? (ss) : i1);                                    \
        i0 = c0 ? (ss) : i0;                                                \
        d2 = c1 ? d1 : (c2 ? (dd) : d2);                                    \
        d1 = c0 ? d0 : (c1 ? (dd) : d1);                                    \
        d0 = c0 ? (dd) : d0;                                                \
    }

// ---------------------------------------------------------------------------
// k_fused (R14 verbatim — best passing build):
//   Phase 1: A-tile staged bf16+swizzled in LDS; B-frags from L2-resident W2t;
//            8 MFMAs -> ori_f tile in registers.
//   Phase 2: wave-parallel 3-NN, 16 queries/block, 16-way split, 4 chunks,
//            unconditional fully-unrolled INS3M + lexicographic butterfly.
//   Phase 3: per-acc-element gather + single coalesced write.
// ---------------------------------------------------------------------------
__global__ __launch_bounds__(256) void k_fused(const float4* __restrict__ dxyzp,
                                               const float4* __restrict__ oxyzp,
                                               const float*  __restrict__ ofeat,
                                               const short*  __restrict__ W2t,
                                               const float*  __restrict__ b2,
                                               const float*  __restrict__ downf,
                                               float*        __restrict__ out) {
    __shared__ __align__(16) char lds[21120];
    short*  sA = reinterpret_cast<short*>(lds);             // [16*128] bf16
    float4* sx = reinterpret_cast<float4*>(lds + 4096);     // [16*65]
    int*    si = reinterpret_cast<int*>(lds + 20736);       // [48]
    float*  sw = reinterpret_cast<float*>(lds + 20928);     // [48]

    const int tid  = threadIdx.x;
    const int lane = tid & 63;
    const int wv   = tid >> 6;
    const int b     = blockIdx.x >> 10;           // 1024 blocks per batch
    const int qbase = (blockIdx.x & 1023) * 16;
    const int lo16 = lane & 15;
    const int hi8  = (lane >> 4) * 8;

    // ---- Phase 1a: stage A-tile (16 rows of ofeat, bf16, XOR-swizzled) ----
    {
        const float4* a4 = reinterpret_cast<const float4*>(
            ofeat + (size_t)(b * N + qbase) * 128);
        const int n    = tid;                     // 256 jobs, 1 per thread
        const int row  = n >> 4;                  // 0..15
        const int k8   = (n & 15) * 8;
        const int base4 = (row * 128 + k8) >> 2;
        const float4 u = a4[base4];
        const float4 v = a4[base4 + 1];
        short8_t s = { (short)f2bf(u.x), (short)f2bf(u.y), (short)f2bf(u.z), (short)f2bf(u.w),
                       (short)f2bf(v.x), (short)f2bf(v.y), (short)f2bf(v.z), (short)f2bf(v.w) };
        const int idx = (row * 128 + k8) ^ ((row & 7) << 3);
        *reinterpret_cast<short8_t*>(&sA[idx]) = s;
    }

    // ---- Phase 1b: B fragments straight from global W2t (L2-resident) ----
    short8_t bfr[4][2];
    #pragma unroll
    for (int c = 0; c < 2; ++c) {
        const int col = wv * 32 + c * 16 + lo16;
        const short* wt = W2t + col * 128;
        #pragma unroll
        for (int ks = 0; ks < 4; ++ks)
            bfr[ks][c] = *reinterpret_cast<const short8_t*>(wt + ks * 32 + hi8);
    }
    __syncthreads();

    // ---- MFMA: acc = ofeat_tile @ W2 (MF=1, KS=4) ----
    f32x4 acc[2] = { (f32x4){0.f,0.f,0.f,0.f}, (f32x4){0.f,0.f,0.f,0.f} };
    const int axor = (lane & 7) << 3;
    #pragma unroll
    for (int ks = 0; ks < 4; ++ks) {
        const int aidx = (lo16 * 128 + ks * 32 + hi8) ^ axor;
        const short8_t af = *reinterpret_cast<const short8_t*>(&sA[aidx]);
        acc[0] = __builtin_amdgcn_mfma_f32_16x16x32_bf16(af, bfr[ks][0], acc[0], 0, 0, 0);
        acc[1] = __builtin_amdgcn_mfma_f32_16x16x32_bf16(af, bfr[ks][1], acc[1], 0, 0, 0);
    }
    __syncthreads();

    // ---- Phase 2: 3-NN search (unconditional, fully-unrolled inserts) ----
    const int sp   = lane & 15;
    const int qs   = lane >> 4;
    const int slot = wv * 4 + qs;                 // 0..15 within block

    const float4 o = oxyzp[(size_t)b * N + qbase + slot];
    const float sumo = __fadd_rn(__fadd_rn(__fmul_rn(o.x, o.x), __fmul_rn(o.y, o.y)),
                                 __fmul_rn(o.z, o.z));

    float a0 = FLT_MAX, a1 = FLT_MAX, a2 = FLT_MAX;
    int   ai0 = 0, ai1 = 0, ai2 = 0;

    const float4* dpb = dxyzp + (size_t)b * S;

    for (int c = 0; c < 4; ++c) {
        if (c > 0) __syncthreads();
        const float4* dpc = dpb + c * 1024;
        for (int j = tid; j < 1024; j += 256) {
            float4 v = dpc[j];
            const float ss = __fadd_rn(__fadd_rn(__fmul_rn(v.x, v.x), __fmul_rn(v.y, v.y)),
                                       __fmul_rn(v.z, v.z));
            float4 w;
            w.x = v.x + v.x;
            w.y = v.y + v.y;
            w.z = v.z + v.z;
            w.w = ss;
            sx[(j >> 6) * 65 + (j & 63)] = w;
        }
        __syncthreads();

        const float4* base = &sx[sp * 65];
        const int g0 = c * 1024 + sp * 64;

        #pragma unroll
        for (int i = 0; i < 64; ++i) {
            const float4 q = base[i];
            const float dot2 = __fadd_rn(__fadd_rn(__fmul_rn(q.x, o.x), __fmul_rn(q.y, o.y)),
                                         __fmul_rn(q.z, o.z));
            const float dd = __fsub_rn(__fadd_rn(sumo, q.w), dot2);
            INS3M(a0, a1, a2, ai0, ai1, ai2, dd, g0 + i);
        }
    }

    #pragma unroll
    for (int m = 1; m <= 8; m <<= 1) {
        const float nd0 = __shfl_xor(a0, m, 64);
        const float nd1 = __shfl_xor(a1, m, 64);
        const float nd2 = __shfl_xor(a2, m, 64);
        const int   ni0 = __shfl_xor(ai0, m, 64);
        const int   ni1 = __shfl_xor(ai1, m, 64);
        const int   ni2 = __shfl_xor(ai2, m, 64);
        INS3L(a0, a1, a2, ai0, ai1, ai2, nd0, ni0);
        INS3L(a0, a1, a2, ai0, ai1, ai2, nd1, ni1);
        INS3L(a0, a1, a2, ai0, ai1, ai2, nd2, ni2);
    }

    if (sp == 0) {
        const float r0 = 1.0f / (a0 + 1e-8f);
        const float r1 = 1.0f / (a1 + 1e-8f);
        const float r2 = 1.0f / (a2 + 1e-8f);
        const float rs = __fadd_rn(__fadd_rn(r0, r1), r2);
        si[slot * 3 + 0] = ai0;
        si[slot * 3 + 1] = ai1;
        si[slot * 3 + 2] = ai2;
        sw[slot * 3 + 0] = r0 / rs;
        sw[slot * 3 + 1] = r1 / rs;
        sw[slot * 3 + 2] = r2 / rs;
    }
    __syncthreads();

    // ---- Phase 3: gather + epilogue, per acc element ----
    const float* df = downf + (size_t)b * S * OUTC;
    float* ob = out + (size_t)(b * N + qbase) * OUTC;

    #pragma unroll
    for (int c = 0; c < 2; ++c) {
        const int col = wv * 32 + c * 16 + lo16;
        const float bb = b2[col];
        #pragma unroll
        for (int r = 0; r < 4; ++r) {
            const int row16 = (lane >> 4) * 4 + r;
            const int   j0 = si[row16 * 3 + 0];
            const int   j1 = si[row16 * 3 + 1];
            const int   j2 = si[row16 * 3 + 2];
            const float w0 = sw[row16 * 3 + 0];
            const float w1 = sw[row16 * 3 + 1];
            const float w2 = sw[row16 * 3 + 2];
            const float g = __fadd_rn(
                __fadd_rn(__fmul_rn(w0, df[(size_t)j0 * OUTC + col]),
                          __fmul_rn(w1, df[(size_t)j1 * OUTC + col])),
                __fmul_rn(w2, df[(size_t)j2 * OUTC + col]));
            ob[(size_t)row16 * OUTC + col] = (acc[c][r] + bb) + g;
        }
    }
}

// ---------------------------------------------------------------------------

extern "C" void kernel_launch(void* const* d_in, const int* in_sizes, int n_in,
                              void* d_out, int out_size, void* d_ws, size_t ws_size,
                              hipStream_t stream) {
    const float* dxyzp = (const float*)d_in[0];   // (B,S,4)
    const float* dfeat = (const float*)d_in[1];   // (B,S,256)
    const float* oxyzp = (const float*)d_in[2];   // (B,N,4)
    const float* ofeat = (const float*)d_in[3];   // (B,N,128)
    const float* W1    = (const float*)d_in[4];   // (256,128)
    const float* b1    = (const float*)d_in[5];   // (128)
    const float* W2    = (const float*)d_in[6];   // (128,128)
    const float* b2    = (const float*)d_in[7];   // (128)

    float* out   = (float*)d_out;                 // (B,N,128)
    char*  ws    = (char*)d_ws;
    float* downf = (float*)(ws + OFF_DOWNF);      // (B,S,128)
    short* W2t   = (short*)(ws + OFF_W2T);        // (128,128) bf16, transposed

    // W2^T bf16 (one-time, tiny)
    k_prep<<<64, 256, 0, stream>>>(W2, W2t);

    // down_f = down_features @ W1 + b1 -> workspace (MFMA bf16, frozen)
    k_mfma<INC, 32><<<(B * S) / 32, 256, 0, stream>>>(dfeat, W1, b1, downf);

    // Fused: ori_f GEMM + 3-NN search + interpolation -> out
    k_fused<<<B * (N / 16), 256, 0, stream>>>(
        (const float4*)dxyzp, (const float4*)oxyzp, ofeat, W2t, b2, downf, out);
}